// Round 1
// baseline (3831.791 us; speedup 1.0000x reference)
//
#include <hip/hip_runtime.h>
#include <hip/hip_bf16.h>

// Problem constants (from reference):
#define BATCH 8
#define NQ    75
#define WAY   5
#define PN    121
#define DIM   640
#define SSZ   605        // shot * patch_num = 5 * 121
#define TOPK  3

// Tiling:
#define TM 128           // rows (query patches, 121 padded to 128)
#define TN 64            // support-patch chunk
#define TK 64            // K chunk
#define NCH ((SSZ + TN - 1) / TN)   // 10
#define KCH (DIM / TK)              // 10
#define QSTR 72          // LDS row stride in bf16 elems (64 + 8 pad -> 2-way bank alias = free)
#define CSTR 67          // LDS row stride for fp32 C staging

typedef __attribute__((ext_vector_type(8))) short   short8;
typedef __attribute__((ext_vector_type(8))) __bf16  bf16x8;
typedef __attribute__((ext_vector_type(4))) float   f32x4;

// fp32 -> bf16 round-to-nearest-even (inputs are finite normals; no NaN path needed)
__device__ inline short f2bf(float f) {
  unsigned u = __builtin_bit_cast(unsigned, f);
  unsigned r = (u + 0x7fffu + ((u >> 16) & 1u)) >> 16;
  return (short)r;
}

// insert v into sorted-descending triple (a >= b >= c)
__device__ inline void ins3(float &a, float &b, float &c, float v) {
  if (v > a)      { c = b; b = a; a = v; }
  else if (v > b) { c = b; b = v; }
  else if (v > c) { c = v; }
}

__global__ __launch_bounds__(256) void lpc_kernel(
    const float* __restrict__ qf,   // [B, NQ, PN, DIM]
    const float* __restrict__ sf,   // [B, WAY, SSZ, DIM] (shot folded into SSZ)
    float* __restrict__ out)        // [B, NQ, WAY]
{
  __shared__ short Qs[TM][QSTR];        // 18432 B
  __shared__ short Ss[TN][QSTR];        //  9216 B
  __shared__ float Cs[TM][CSTR];        // 34304 B
  __shared__ float top3[TM][TOPK];      //  1536 B
  __shared__ float red[4];

  const int bid = blockIdx.x;
  const int w   = bid % WAY;
  const int qi  = (bid / WAY) % NQ;
  const int b   = bid / (WAY * NQ);

  const float* Qb = qf + ((size_t)(b * NQ + qi)) * PN * DIM;
  const float* Sb = sf + ((size_t)(b * WAY + w)) * SSZ * DIM;

  const int tid  = threadIdx.x;
  const int lane = tid & 63;
  const int wv   = tid >> 6;        // wave 0..3
  const int l15  = lane & 15;       // A-row (m) for A frag, B-row (n) for B frag, col (n) for C
  const int quad = lane >> 4;       // 0..3

  if (tid < TM) {
    top3[tid][0] = -3.0e38f; top3[tid][1] = -3.0e38f; top3[tid][2] = -3.0e38f;
  }

  f32x4 acc[2][4];

  for (int nc = 0; nc < NCH; ++nc) {
    const int sbase = nc * TN;
    int vn = SSZ - sbase; if (vn > TN) vn = TN;

    #pragma unroll
    for (int mt = 0; mt < 2; ++mt)
      #pragma unroll
      for (int nt = 0; nt < 4; ++nt)
        acc[mt][nt] = (f32x4){0.f, 0.f, 0.f, 0.f};

    for (int kc = 0; kc < KCH; ++kc) {
      const int kbase = kc * TK;
      __syncthreads();   // protect Qs/Ss from readers of previous iteration

      // stage Q tile: TM x TK fp32 -> bf16. 16 threads per row, 8 rows-passes.
      #pragma unroll
      for (int i = 0; i < 8; ++i) {
        int lin = i * 256 + tid;
        int row = lin >> 4;
        int c4  = lin & 15;
        float4 v = make_float4(0.f, 0.f, 0.f, 0.f);
        if (row < PN)
          v = *reinterpret_cast<const float4*>(Qb + (size_t)row * DIM + kbase + c4 * 4);
        short4 h;
        h.x = f2bf(v.x); h.y = f2bf(v.y); h.z = f2bf(v.z); h.w = f2bf(v.w);
        *reinterpret_cast<short4*>(&Qs[row][c4 * 4]) = h;
      }
      // stage S tile: TN x TK
      #pragma unroll
      for (int i = 0; i < 4; ++i) {
        int lin  = i * 256 + tid;
        int row  = lin >> 4;
        int c4   = lin & 15;
        int srow = sbase + row;
        float4 v = make_float4(0.f, 0.f, 0.f, 0.f);
        if (srow < SSZ)
          v = *reinterpret_cast<const float4*>(Sb + (size_t)srow * DIM + kbase + c4 * 4);
        short4 h;
        h.x = f2bf(v.x); h.y = f2bf(v.y); h.z = f2bf(v.z); h.w = f2bf(v.w);
        *reinterpret_cast<short4*>(&Ss[row][c4 * 4]) = h;
      }
      __syncthreads();

      // MFMA: wave wv owns rows [wv*32, wv*32+32), all 64 cols.
      #pragma unroll
      for (int kk = 0; kk < 2; ++kk) {
        bf16x8 a0 = __builtin_bit_cast(bf16x8,
            *reinterpret_cast<const short8*>(&Qs[wv * 32 +  0 + l15][kk * 32 + quad * 8]));
        bf16x8 a1 = __builtin_bit_cast(bf16x8,
            *reinterpret_cast<const short8*>(&Qs[wv * 32 + 16 + l15][kk * 32 + quad * 8]));
        #pragma unroll
        for (int nt = 0; nt < 4; ++nt) {
          bf16x8 bb = __builtin_bit_cast(bf16x8,
              *reinterpret_cast<const short8*>(&Ss[nt * 16 + l15][kk * 32 + quad * 8]));
          acc[0][nt] = __builtin_amdgcn_mfma_f32_16x16x32_bf16(a0, bb, acc[0][nt], 0, 0, 0);
          acc[1][nt] = __builtin_amdgcn_mfma_f32_16x16x32_bf16(a1, bb, acc[1][nt], 0, 0, 0);
        }
      }
    }

    // epilogue: C tile -> LDS.  C/D layout: col = lane&15, row = quad*4 + reg  [m89/m91]
    #pragma unroll
    for (int mt = 0; mt < 2; ++mt)
      #pragma unroll
      for (int nt = 0; nt < 4; ++nt)
        #pragma unroll
        for (int r = 0; r < 4; ++r)
          Cs[wv * 32 + mt * 16 + quad * 4 + r][nt * 16 + l15] = acc[mt][nt][r];
    __syncthreads();

    // running top-3 per row: 2 threads/row, 32 cols each
    {
      int row  = tid >> 1;
      int half = tid & 1;
      float t0 = -3.0e38f, t1 = -3.0e38f, t2 = -3.0e38f;
      int c0   = half * 32;
      int cend = c0 + 32; if (cend > vn) cend = vn;
      for (int c = c0; c < cend; ++c)
        ins3(t0, t1, t2, Cs[row][c]);
      // merge with partner thread (adjacent lane, same wave)
      float o0 = __shfl_xor(t0, 1);
      float o1 = __shfl_xor(t1, 1);
      float o2 = __shfl_xor(t2, 1);
      ins3(t0, t1, t2, o0); ins3(t0, t1, t2, o1); ins3(t0, t1, t2, o2);
      if (half == 0) {
        float r0 = top3[row][0], r1 = top3[row][1], r2 = top3[row][2];
        ins3(r0, r1, r2, t0); ins3(r0, r1, r2, t1); ins3(r0, r1, r2, t2);
        top3[row][0] = r0; top3[row][1] = r1; top3[row][2] = r2;
      }
    }
    __syncthreads();
  }

  // final: mean of top3 over valid rows
  float s = 0.f;
  for (int i = tid; i < PN * TOPK; i += 256)
    s += top3[i / TOPK][i % TOPK];
  #pragma unroll
  for (int off = 32; off > 0; off >>= 1)
    s += __shfl_down(s, off);
  if (lane == 0) red[wv] = s;
  __syncthreads();
  if (tid == 0)
    out[bid] = (red[0] + red[1] + red[2] + red[3]) * (1.0f / (PN * TOPK));
}

extern "C" void kernel_launch(void* const* d_in, const int* in_sizes, int n_in,
                              void* d_out, int out_size, void* d_ws, size_t ws_size,
                              hipStream_t stream) {
  const float* qf = (const float*)d_in[0];   // [8,75,121,640] fp32
  const float* sf = (const float*)d_in[1];   // [8,5,5,121,640] fp32
  float* out = (float*)d_out;                // [8,75,5] fp32
  (void)in_sizes; (void)n_in; (void)out_size; (void)d_ws; (void)ws_size;
  dim3 grid(BATCH * NQ * WAY);               // 3000 blocks, one per (b,q,w)
  dim3 block(256);
  lpc_kernel<<<grid, block, 0, stream>>>(qf, sf, out);
}

// Round 2
// 773.368 us; speedup vs baseline: 4.9547x; 4.9547x over previous
//
#include <hip/hip_runtime.h>
#include <hip/hip_bf16.h>

// Problem constants:
#define BATCH 8
#define NQ    75
#define WAY   5
#define PN    121
#define DIM   640
#define SSZ   605        // shot * patch_num = 5 * 121
#define TOPK  3

// Main-kernel tiling:
#define TM 128           // query patches per block (121 padded to 128)
#define TN 128           // support-patch chunk (605 padded to 640 in ws)
#define BK 64            // K chunk
#define NCH 5            // 640 / TN
#define KCH 10           // DIM / BK
#define QSTR 72          // LDS row stride (shorts): 144 B -> row step = 4 banks -> worst 2-way (free, m136)

// Workspace layout (bf16, padded, zero-filled pads):
//   Q: [B*NQ][128][640]   = 98,304,000 B
//   S: [B*WAY][640][640]  = 32,768,000 B
#define WSQ_ELEMS ((size_t)BATCH * NQ * TM * DIM)          // 49,152,000
#define WSS_ELEMS ((size_t)BATCH * WAY * 640 * DIM)        // 16,384,000
#define WS_NEED   ((WSQ_ELEMS + WSS_ELEMS) * 2)            // 131,072,000 B

typedef __attribute__((ext_vector_type(8))) short   short8;
typedef __attribute__((ext_vector_type(8))) __bf16  bf16x8;
typedef __attribute__((ext_vector_type(4))) float   f32x4;

// fp32 -> bf16 round-to-nearest-even
__device__ inline unsigned short f2bf(float f) {
  unsigned u = __builtin_bit_cast(unsigned, f);
  return (unsigned short)((u + 0x7fffu + ((u >> 16) & 1u)) >> 16);
}

// branchless insert v into sorted-descending triple (a>=b>=c): 1 max + 2 med3
__device__ inline void ins3(float &a, float &b, float &c, float v) {
  float na = fmaxf(a, v);
  float nb = __builtin_amdgcn_fmed3f(v, a, b);
  float nc2 = __builtin_amdgcn_fmed3f(v, b, c);
  a = na; b = nb; c = nc2;
}

// ---------------- convert kernels: fp32 -> padded bf16 in ws ----------------

__global__ __launch_bounds__(256) void cvt_q(const float* __restrict__ qf,
                                             unsigned short* __restrict__ dst) {
  int idx = blockIdx.x * 256 + threadIdx.x;     // one float4-chunk per thread
  int c4  = idx % 160;                          // 640/4 chunks per row
  int row = (idx / 160) & 127;                  // padded row 0..127
  int bq  = idx / (160 * 128);                  // 0..599
  float4 v = make_float4(0.f, 0.f, 0.f, 0.f);
  if (row < PN)
    v = *reinterpret_cast<const float4*>(qf + ((size_t)(bq * PN + row) * DIM + c4 * 4));
  ushort4 h;
  h.x = f2bf(v.x); h.y = f2bf(v.y); h.z = f2bf(v.z); h.w = f2bf(v.w);
  *reinterpret_cast<ushort4*>(dst + (size_t)idx * 4) = h;
}

__global__ __launch_bounds__(256) void cvt_s(const float* __restrict__ sf,
                                             unsigned short* __restrict__ dst) {
  int idx = blockIdx.x * 256 + threadIdx.x;
  int c4  = idx % 160;
  int row = (idx / 160) % 640;                  // padded row 0..639
  int bw  = idx / (160 * 640);                  // 0..39
  float4 v = make_float4(0.f, 0.f, 0.f, 0.f);
  if (row < SSZ)
    v = *reinterpret_cast<const float4*>(sf + ((size_t)(bw * SSZ + row) * DIM + c4 * 4));
  ushort4 h;
  h.x = f2bf(v.x); h.y = f2bf(v.y); h.z = f2bf(v.z); h.w = f2bf(v.w);
  *reinterpret_cast<ushort4*>(dst + (size_t)idx * 4) = h;
}

// ---------------- main kernel ----------------
// One block per (b, q, w). M=128(121), N=640(605), K=640 GEMM fused with
// per-row running top-3 kept entirely in registers (C/D layout m89/m91:
// col=lane&15, row=quad*4+reg).

__global__ __launch_bounds__(256) void lpc_main(
    const short* __restrict__ wq,   // [600][128][640] bf16, rows 121..127 zero
    const short* __restrict__ wsp,  // [40][640][640] bf16, rows 605..639 zero
    float* __restrict__ out)        // [B, NQ, WAY]
{
  __shared__ short Qs[TM][QSTR];        // 18432 B
  __shared__ short Ss[TN][QSTR];        // 18432 B
  __shared__ float t3row[TM][TOPK];     //  1536 B
  __shared__ float red[4];

  const int bid = blockIdx.x;
  const int w   = bid % WAY;
  const int bq  = bid / WAY;            // b*NQ + q
  const int b   = bid / (WAY * NQ);

  const short* Qb = wq  + (size_t)bq * TM * DIM;
  const short* Sb = wsp + (size_t)(b * WAY + w) * 640 * DIM;

  const int tid  = threadIdx.x;
  const int lane = tid & 63;
  const int wv   = tid >> 6;            // wave 0..3: rows wv*32..wv*32+31
  const int l15  = lane & 15;
  const int quad = lane >> 4;

  // per-lane running top-3 for the 8 owned rows: row = wv*32 + mt*16 + quad*4 + r
  float t0[2][4], t1[2][4], t2[2][4];
  #pragma unroll
  for (int mt = 0; mt < 2; ++mt)
    #pragma unroll
    for (int r = 0; r < 4; ++r) {
      t0[mt][r] = -3.0e38f; t1[mt][r] = -3.0e38f; t2[mt][r] = -3.0e38f;
    }

  for (int nc = 0; nc < NCH; ++nc) {
    f32x4 acc[2][8];
    #pragma unroll
    for (int mt = 0; mt < 2; ++mt)
      #pragma unroll
      for (int nt = 0; nt < 8; ++nt)
        acc[mt][nt] = (f32x4){0.f, 0.f, 0.f, 0.f};

    for (int kc = 0; kc < KCH; ++kc) {
      const int kbase = kc * BK;
      __syncthreads();   // protect Qs/Ss from previous iteration's readers

      // stage Q tile 128x64 and S tile 128x64 (pure bf16 copies, 16 B/lane)
      #pragma unroll
      for (int i = 0; i < 4; ++i) {
        int lin = i * 256 + tid;
        int row = lin >> 3;
        int ch  = lin & 7;
        float4 v = *reinterpret_cast<const float4*>(Qb + (size_t)row * DIM + kbase + ch * 8);
        *reinterpret_cast<float4*>(&Qs[row][ch * 8]) = v;
      }
      #pragma unroll
      for (int i = 0; i < 4; ++i) {
        int lin = i * 256 + tid;
        int row = lin >> 3;
        int ch  = lin & 7;
        float4 v = *reinterpret_cast<const float4*>(Sb + (size_t)(nc * TN + row) * DIM + kbase + ch * 8);
        *reinterpret_cast<float4*>(&Ss[row][ch * 8]) = v;
      }
      __syncthreads();

      #pragma unroll
      for (int kk = 0; kk < 2; ++kk) {
        bf16x8 a0 = __builtin_bit_cast(bf16x8,
            *reinterpret_cast<const short8*>(&Qs[wv * 32 +  0 + l15][kk * 32 + quad * 8]));
        bf16x8 a1 = __builtin_bit_cast(bf16x8,
            *reinterpret_cast<const short8*>(&Qs[wv * 32 + 16 + l15][kk * 32 + quad * 8]));
        #pragma unroll
        for (int nt = 0; nt < 8; ++nt) {
          bf16x8 bb = __builtin_bit_cast(bf16x8,
              *reinterpret_cast<const short8*>(&Ss[nt * 16 + l15][kk * 32 + quad * 8]));
          acc[0][nt] = __builtin_amdgcn_mfma_f32_16x16x32_bf16(a0, bb, acc[0][nt], 0, 0, 0);
          acc[1][nt] = __builtin_amdgcn_mfma_f32_16x16x32_bf16(a1, bb, acc[1][nt], 0, 0, 0);
        }
      }
    }

    // fold this N-chunk into the register top-3 (mask pad cols >= 605)
    #pragma unroll
    for (int nt = 0; nt < 8; ++nt) {
      int col = nc * TN + nt * 16 + l15;
      bool valid = col < SSZ;
      #pragma unroll
      for (int mt = 0; mt < 2; ++mt)
        #pragma unroll
        for (int r = 0; r < 4; ++r) {
          float v = valid ? acc[mt][nt][r] : -3.0e38f;
          ins3(t0[mt][r], t1[mt][r], t2[mt][r], v);
        }
    }
  }

  // merge top-3 across the 16 lanes of each quad-group (butterfly)
  #pragma unroll
  for (int m = 1; m < 16; m <<= 1) {
    #pragma unroll
    for (int mt = 0; mt < 2; ++mt)
      #pragma unroll
      for (int r = 0; r < 4; ++r) {
        float o0 = __shfl_xor(t0[mt][r], m);
        float o1 = __shfl_xor(t1[mt][r], m);
        float o2 = __shfl_xor(t2[mt][r], m);
        ins3(t0[mt][r], t1[mt][r], t2[mt][r], o0);
        ins3(t0[mt][r], t1[mt][r], t2[mt][r], o1);
        ins3(t0[mt][r], t1[mt][r], t2[mt][r], o2);
      }
  }
  __syncthreads();   // Qs/Ss done; t3row region safe to write
  if (l15 == 0) {
    #pragma unroll
    for (int mt = 0; mt < 2; ++mt)
      #pragma unroll
      for (int r = 0; r < 4; ++r) {
        int row = wv * 32 + mt * 16 + quad * 4 + r;
        t3row[row][0] = t0[mt][r];
        t3row[row][1] = t1[mt][r];
        t3row[row][2] = t2[mt][r];
      }
  }
  __syncthreads();

  // mean over valid rows (<121) and k
  float s = 0.f;
  for (int i = tid; i < PN * TOPK; i += 256)
    s += t3row[i / TOPK][i % TOPK];
  #pragma unroll
  for (int off = 32; off > 0; off >>= 1)
    s += __shfl_down(s, off);
  if (lane == 0) red[wv] = s;
  __syncthreads();
  if (tid == 0)
    out[bid] = (red[0] + red[1] + red[2] + red[3]) * (1.0f / (PN * TOPK));
}

// ---------------- fallback (round-1 kernel, used only if ws too small) ------

#define FTN 64
#define FQSTR 72
#define FCSTR 67

__global__ __launch_bounds__(256) void lpc_fallback(
    const float* __restrict__ qf, const float* __restrict__ sf,
    float* __restrict__ out)
{
  __shared__ short Qs[TM][FQSTR];
  __shared__ short Ss[FTN][FQSTR];
  __shared__ float Cs[TM][FCSTR];
  __shared__ float top3[TM][TOPK];
  __shared__ float red[4];

  const int bid = blockIdx.x;
  const int w   = bid % WAY;
  const int qi  = (bid / WAY) % NQ;
  const int b   = bid / (WAY * NQ);
  const float* Qb = qf + ((size_t)(b * NQ + qi)) * PN * DIM;
  const float* Sb = sf + ((size_t)(b * WAY + w)) * SSZ * DIM;
  const int tid  = threadIdx.x;
  const int lane = tid & 63;
  const int wv   = tid >> 6;
  const int l15  = lane & 15;
  const int quad = lane >> 4;

  if (tid < TM) { top3[tid][0] = -3.0e38f; top3[tid][1] = -3.0e38f; top3[tid][2] = -3.0e38f; }
  f32x4 acc[2][4];
  for (int nc = 0; nc < 10; ++nc) {
    const int sbase = nc * FTN;
    int vn = SSZ - sbase; if (vn > FTN) vn = FTN;
    #pragma unroll
    for (int mt = 0; mt < 2; ++mt)
      #pragma unroll
      for (int nt = 0; nt < 4; ++nt) acc[mt][nt] = (f32x4){0.f,0.f,0.f,0.f};
    for (int kc = 0; kc < KCH; ++kc) {
      const int kbase = kc * BK;
      __syncthreads();
      #pragma unroll
      for (int i = 0; i < 8; ++i) {
        int lin = i * 256 + tid; int row = lin >> 4; int c4 = lin & 15;
        float4 v = make_float4(0.f,0.f,0.f,0.f);
        if (row < PN) v = *reinterpret_cast<const float4*>(Qb + (size_t)row * DIM + kbase + c4 * 4);
        ushort4 h; h.x=f2bf(v.x); h.y=f2bf(v.y); h.z=f2bf(v.z); h.w=f2bf(v.w);
        *reinterpret_cast<ushort4*>(&Qs[row][c4*4]) = h;
      }
      #pragma unroll
      for (int i = 0; i < 4; ++i) {
        int lin = i * 256 + tid; int row = lin >> 4; int c4 = lin & 15;
        int srow = sbase + row;
        float4 v = make_float4(0.f,0.f,0.f,0.f);
        if (srow < SSZ) v = *reinterpret_cast<const float4*>(Sb + (size_t)srow * DIM + kbase + c4 * 4);
        ushort4 h; h.x=f2bf(v.x); h.y=f2bf(v.y); h.z=f2bf(v.z); h.w=f2bf(v.w);
        *reinterpret_cast<ushort4*>(&Ss[row][c4*4]) = h;
      }
      __syncthreads();
      #pragma unroll
      for (int kk = 0; kk < 2; ++kk) {
        bf16x8 a0 = __builtin_bit_cast(bf16x8, *reinterpret_cast<const short8*>(&Qs[wv*32+ 0+l15][kk*32+quad*8]));
        bf16x8 a1 = __builtin_bit_cast(bf16x8, *reinterpret_cast<const short8*>(&Qs[wv*32+16+l15][kk*32+quad*8]));
        #pragma unroll
        for (int nt = 0; nt < 4; ++nt) {
          bf16x8 bb = __builtin_bit_cast(bf16x8, *reinterpret_cast<const short8*>(&Ss[nt*16+l15][kk*32+quad*8]));
          acc[0][nt] = __builtin_amdgcn_mfma_f32_16x16x32_bf16(a0, bb, acc[0][nt], 0,0,0);
          acc[1][nt] = __builtin_amdgcn_mfma_f32_16x16x32_bf16(a1, bb, acc[1][nt], 0,0,0);
        }
      }
    }
    #pragma unroll
    for (int mt = 0; mt < 2; ++mt)
      #pragma unroll
      for (int nt = 0; nt < 4; ++nt)
        #pragma unroll
        for (int r = 0; r < 4; ++r)
          Cs[wv*32+mt*16+quad*4+r][nt*16+l15] = acc[mt][nt][r];
    __syncthreads();
    {
      int row = tid >> 1; int half = tid & 1;
      float a = -3.0e38f, bb2 = -3.0e38f, c = -3.0e38f;
      int c0 = half * 32; int cend = c0 + 32; if (cend > vn) cend = vn;
      for (int cc = c0; cc < cend; ++cc) ins3(a, bb2, c, Cs[row][cc]);
      float o0 = __shfl_xor(a,1), o1 = __shfl_xor(bb2,1), o2 = __shfl_xor(c,1);
      ins3(a,bb2,c,o0); ins3(a,bb2,c,o1); ins3(a,bb2,c,o2);
      if (half == 0) {
        float r0=top3[row][0], r1=top3[row][1], r2=top3[row][2];
        ins3(r0,r1,r2,a); ins3(r0,r1,r2,bb2); ins3(r0,r1,r2,c);
        top3[row][0]=r0; top3[row][1]=r1; top3[row][2]=r2;
      }
    }
    __syncthreads();
  }
  float s = 0.f;
  for (int i = tid; i < PN * TOPK; i += 256) s += top3[i/TOPK][i%TOPK];
  #pragma unroll
  for (int off = 32; off > 0; off >>= 1) s += __shfl_down(s, off);
  if (lane == 0) red[wv] = s;
  __syncthreads();
  if (tid == 0) out[bid] = (red[0]+red[1]+red[2]+red[3]) * (1.0f/(PN*TOPK));
}

// ---------------- launch ----------------

extern "C" void kernel_launch(void* const* d_in, const int* in_sizes, int n_in,
                              void* d_out, int out_size, void* d_ws, size_t ws_size,
                              hipStream_t stream) {
  const float* qf = (const float*)d_in[0];   // [8,75,121,640] fp32
  const float* sf = (const float*)d_in[1];   // [8,5,5,121,640] fp32
  float* out = (float*)d_out;                // [8,75,5] fp32
  (void)in_sizes; (void)n_in; (void)out_size;

  if (ws_size >= WS_NEED && d_ws != nullptr) {
    unsigned short* wq = (unsigned short*)d_ws;
    unsigned short* ws = wq + WSQ_ELEMS;
    cvt_q<<<48000, 256, 0, stream>>>(qf, wq);                 // 12,288,000 chunks
    cvt_s<<<16000, 256, 0, stream>>>(sf, ws);                 //  4,096,000 chunks
    lpc_main<<<BATCH * NQ * WAY, 256, 0, stream>>>((const short*)wq, (const short*)ws, out);
  } else {
    lpc_fallback<<<BATCH * NQ * WAY, 256, 0, stream>>>(qf, sf, out);
  }
}

// Round 3
// 758.629 us; speedup vs baseline: 5.0509x; 1.0194x over previous
//
#include <hip/hip_runtime.h>
#include <hip/hip_bf16.h>

// Problem constants:
#define BATCH 8
#define NQ    75
#define WAY   5
#define PN    121
#define DIM   640
#define SSZ   605        // shot * patch_num
#define TOPK  3

#define KCH 10           // DIM / 64
#define NCH 5            // 640 / 128

// Workspace: bf16, MFMA-tile-packed, XOR-swizzled (chunk_phys = chunk_log ^ (row&7)).
//   Q: [bq=600][kc=10][row=128][chunk=8]x16B  = 98,304,000 B
//   S: [bw=40][nc=5][kc=10][row=128][chunk=8] = 32,768,000 B
#define NQCH  (600 * 10 * 128 * 8)       // 6,144,000 Q chunks
#define NSCH  (40 * 5 * 10 * 128 * 8)    // 2,048,000 S chunks
#define TOTCH (NQCH + NSCH)              // 8,192,000
#define WSQ_BYTES ((size_t)NQCH * 16)
#define WS_NEED   ((size_t)TOTCH * 16)   // 131,072,000 B (same as round 2 — proven fit)

typedef __attribute__((ext_vector_type(8))) short   short8;
typedef __attribute__((ext_vector_type(8))) __bf16  bf16x8;
typedef __attribute__((ext_vector_type(4))) float   f32x4;

__device__ inline unsigned short f2bf(float f) {
  unsigned u = __builtin_bit_cast(unsigned, f);
  return (unsigned short)((u + 0x7fffu + ((u >> 16) & 1u)) >> 16);
}

// branchless insert into sorted-descending triple: 1 max + 2 med3
__device__ inline void ins3(float &a, float &b, float &c, float v) {
  float na  = fmaxf(a, v);
  float nb  = __builtin_amdgcn_fmed3f(v, a, b);
  float nc2 = __builtin_amdgcn_fmed3f(v, b, c);
  a = na; b = nb; c = nc2;
}

// async 16B global->LDS (DMA; LDS dest = wave-uniform base + lane*16)
__device__ inline void async_copy16(const void* g, void* l) {
  __builtin_amdgcn_global_load_lds(
      (const __attribute__((address_space(1))) unsigned int*)g,
      (__attribute__((address_space(3))) unsigned int*)l, 16, 0, 0);
}

// ---------------- pack kernel: fp32 -> swizzled bf16 tiles in ws -------------
// One thread per 16-B output chunk; writes perfectly coalesced.
__global__ __launch_bounds__(256) void cvt_pack(const float* __restrict__ qf,
                                                const float* __restrict__ sf,
                                                unsigned short* __restrict__ wq,
                                                unsigned short* __restrict__ wsp) {
  int idx = blockIdx.x * 256 + threadIdx.x;
  union { ushort4 h[2]; uint4 v; } o;
  o.v = make_uint4(0u, 0u, 0u, 0u);
  if (idx < NQCH) {
    int p   = idx & 7;
    int row = (idx >> 3) & 127;
    int t   = idx >> 10;
    int kc  = t % KCH;
    int bq  = t / KCH;
    int c   = p ^ (row & 7);
    if (row < PN) {
      const float* g = qf + ((size_t)bq * PN + row) * DIM + kc * 64 + c * 8;
      float4 v0 = reinterpret_cast<const float4*>(g)[0];
      float4 v1 = reinterpret_cast<const float4*>(g)[1];
      o.h[0] = make_ushort4(f2bf(v0.x), f2bf(v0.y), f2bf(v0.z), f2bf(v0.w));
      o.h[1] = make_ushort4(f2bf(v1.x), f2bf(v1.y), f2bf(v1.z), f2bf(v1.w));
    }
    reinterpret_cast<uint4*>(wq)[idx] = o.v;
  } else if (idx < TOTCH) {
    int si  = idx - NQCH;
    int p   = si & 7;
    int row = (si >> 3) & 127;
    int t   = si >> 10;
    int kc  = t % KCH;
    int u   = t / KCH;
    int nc  = u % NCH;
    int bw  = u / NCH;
    int srow = nc * 128 + row;
    int c   = p ^ (row & 7);
    if (srow < SSZ) {
      const float* g = sf + ((size_t)bw * SSZ + srow) * DIM + kc * 64 + c * 8;
      float4 v0 = reinterpret_cast<const float4*>(g)[0];
      float4 v1 = reinterpret_cast<const float4*>(g)[1];
      o.h[0] = make_ushort4(f2bf(v0.x), f2bf(v0.y), f2bf(v0.z), f2bf(v0.w));
      o.h[1] = make_ushort4(f2bf(v1.x), f2bf(v1.y), f2bf(v1.z), f2bf(v1.w));
    }
    reinterpret_cast<uint4*>(wsp)[si] = o.v;
  }
}

// ---------------- main kernel ----------------
// One block per (b,q,w). 4 waves = 64x64 quadrants of the 128x128 tile.
// global_load_lds DMA staging; XOR-swizzled fragment reads (conflict-mitigated);
// per-row top-3 in registers; fold per 128-col chunk.
__global__ __launch_bounds__(256) void lpc_main(
    const char* __restrict__ wq,    // packed Q tiles
    const char* __restrict__ wsp,   // packed S tiles
    float* __restrict__ out)        // [B, NQ, WAY]
{
  __shared__ char Qs[16384];
  __shared__ char Ss[16384];
  __shared__ float red[4];

  const int bid = blockIdx.x;
  const int w   = bid % WAY;
  const int bq  = bid / WAY;            // b*NQ + q
  const int b   = bid / (WAY * NQ);

  const char* Qtiles = wq  + (size_t)bq * KCH * 16384;
  const char* Stiles = wsp + (size_t)(b * WAY + w) * NCH * KCH * 16384;

  const int tid  = threadIdx.x;
  const int lane = tid & 63;
  const int wv   = tid >> 6;
  const int l15  = lane & 15;
  const int quad = lane >> 4;
  const int mrow0 = (wv >> 1) * 64;     // quadrant row base
  const int ncol0 = (wv & 1) * 64;      // quadrant col base

  // swizzled chunk byte offsets (XOR distributes over the <<4)
  const int sw16 = (l15 & 7) * 16;
  const int cp0  = (quad * 16) ^ sw16;        // kk = 0
  const int cp1  = ((4 + quad) * 16) ^ sw16;  // kk = 1

  const char* qb = Qs + (mrow0 + l15) * 128;
  const char* sb = Ss + (ncol0 + l15) * 128;

  // per-lane running top-3 for 16 owned rows: row = mrow0 + mt*16 + quad*4 + r
  float t3a[4][4], t3b[4][4], t3c[4][4];
  #pragma unroll
  for (int mt = 0; mt < 4; ++mt)
    #pragma unroll
    for (int r = 0; r < 4; ++r) {
      t3a[mt][r] = -3.0e38f; t3b[mt][r] = -3.0e38f; t3c[mt][r] = -3.0e38f;
    }

  for (int nc = 0; nc < NCH; ++nc) {
    f32x4 acc[4][4];
    #pragma unroll
    for (int mt = 0; mt < 4; ++mt)
      #pragma unroll
      for (int nt = 0; nt < 4; ++nt)
        acc[mt][nt] = (f32x4){0.f, 0.f, 0.f, 0.f};

    #pragma unroll 1
    for (int kc = 0; kc < KCH; ++kc) {
      __syncthreads();   // previous iteration's readers done
      // DMA stage: 16 KB Q tile + 16 KB S tile, 4+4 issues per wave
      {
        const char* qsl = Qtiles + (size_t)kc * 16384;
        const char* ssl = Stiles + ((size_t)nc * KCH + kc) * 16384;
        #pragma unroll
        for (int i = 0; i < 4; ++i) {
          int ch = wv * 4 + i;
          async_copy16(qsl + ch * 1024 + lane * 16, Qs + ch * 1024);
          async_copy16(ssl + ch * 1024 + lane * 16, Ss + ch * 1024);
        }
      }
      __syncthreads();   // drains vmcnt (DMA complete)

      #pragma unroll
      for (int kk = 0; kk < 2; ++kk) {
        const int cp = kk ? cp1 : cp0;
        short8 a[4], bf[4];
        #pragma unroll
        for (int mt = 0; mt < 4; ++mt)
          a[mt] = *reinterpret_cast<const short8*>(qb + mt * 2048 + cp);
        #pragma unroll
        for (int nt = 0; nt < 4; ++nt)
          bf[nt] = *reinterpret_cast<const short8*>(sb + nt * 2048 + cp);
        #pragma unroll
        for (int mt = 0; mt < 4; ++mt)
          #pragma unroll
          for (int nt = 0; nt < 4; ++nt)
            acc[mt][nt] = __builtin_amdgcn_mfma_f32_16x16x32_bf16(
                __builtin_bit_cast(bf16x8, a[mt]),
                __builtin_bit_cast(bf16x8, bf[nt]), acc[mt][nt], 0, 0, 0);
      }
    }

    // fold this 128-col chunk into register top-3 (mask pad cols >= 605)
    #pragma unroll
    for (int nt = 0; nt < 4; ++nt) {
      int col = nc * 128 + ncol0 + nt * 16 + l15;
      bool valid = col < SSZ;
      #pragma unroll
      for (int mt = 0; mt < 4; ++mt)
        #pragma unroll
        for (int r = 0; r < 4; ++r) {
          float v = valid ? acc[mt][nt][r] : -3.0e38f;
          ins3(t3a[mt][r], t3b[mt][r], t3c[mt][r], v);
        }
    }
  }

  // butterfly-merge top-3 across the 16 l15 lanes (same rows, different cols)
  #pragma unroll
  for (int m = 1; m < 16; m <<= 1) {
    #pragma unroll
    for (int mt = 0; mt < 4; ++mt)
      #pragma unroll
      for (int r = 0; r < 4; ++r) {
        float o0 = __shfl_xor(t3a[mt][r], m);
        float o1 = __shfl_xor(t3b[mt][r], m);
        float o2 = __shfl_xor(t3c[mt][r], m);
        ins3(t3a[mt][r], t3b[mt][r], t3c[mt][r], o0);
        ins3(t3a[mt][r], t3b[mt][r], t3c[mt][r], o1);
        ins3(t3a[mt][r], t3b[mt][r], t3c[mt][r], o2);
      }
  }

  // cross-half merge via LDS scratch (reuse Qs): waves 1,3 publish; 0,2 merge
  float* tb = reinterpret_cast<float*>(Qs);   // [128][3]
  __syncthreads();
  if ((wv & 1) == 1 && l15 == 0) {
    #pragma unroll
    for (int mt = 0; mt < 4; ++mt)
      #pragma unroll
      for (int r = 0; r < 4; ++r) {
        int row = mrow0 + mt * 16 + quad * 4 + r;
        tb[row * 3 + 0] = t3a[mt][r];
        tb[row * 3 + 1] = t3b[mt][r];
        tb[row * 3 + 2] = t3c[mt][r];
      }
  }
  __syncthreads();
  if ((wv & 1) == 0 && l15 == 0) {
    #pragma unroll
    for (int mt = 0; mt < 4; ++mt)
      #pragma unroll
      for (int r = 0; r < 4; ++r) {
        int row = mrow0 + mt * 16 + quad * 4 + r;
        ins3(t3a[mt][r], t3b[mt][r], t3c[mt][r], tb[row * 3 + 0]);
        ins3(t3a[mt][r], t3b[mt][r], t3c[mt][r], tb[row * 3 + 1]);
        ins3(t3a[mt][r], t3b[mt][r], t3c[mt][r], tb[row * 3 + 2]);
      }
  }
  __syncthreads();
  if ((wv & 1) == 0 && l15 == 0) {
    #pragma unroll
    for (int mt = 0; mt < 4; ++mt)
      #pragma unroll
      for (int r = 0; r < 4; ++r) {
        int row = mrow0 + mt * 16 + quad * 4 + r;
        tb[row * 3 + 0] = t3a[mt][r];
        tb[row * 3 + 1] = t3b[mt][r];
        tb[row * 3 + 2] = t3c[mt][r];
      }
  }
  __syncthreads();

  // mean over valid rows (<121) and k
  float s = 0.f;
  for (int i = tid; i < PN * TOPK; i += 256) s += tb[i];
  #pragma unroll
  for (int off = 32; off > 0; off >>= 1) s += __shfl_down(s, off);
  if (lane == 0) red[wv] = s;
  __syncthreads();
  if (tid == 0)
    out[bid] = (red[0] + red[1] + red[2] + red[3]) * (1.0f / (PN * TOPK));
}

// ---------------- fallback (direct from fp32, only if ws too small) ---------
__global__ __launch_bounds__(256) void lpc_fallback(
    const float* __restrict__ qf, const float* __restrict__ sf,
    float* __restrict__ out)
{
  __shared__ short Qst[128][72];
  __shared__ short Sst[64][72];
  __shared__ float Cs[128][67];
  __shared__ float top3[128][TOPK];
  __shared__ float red[4];

  const int bid = blockIdx.x;
  const int w   = bid % WAY;
  const int qi  = (bid / WAY) % NQ;
  const int b   = bid / (WAY * NQ);
  const float* Qb = qf + ((size_t)(b * NQ + qi)) * PN * DIM;
  const float* Sb = sf + ((size_t)(b * WAY + w)) * SSZ * DIM;
  const int tid  = threadIdx.x;
  const int lane = tid & 63;
  const int wv   = tid >> 6;
  const int l15  = lane & 15;
  const int quad = lane >> 4;

  if (tid < 128) { top3[tid][0] = -3.0e38f; top3[tid][1] = -3.0e38f; top3[tid][2] = -3.0e38f; }
  f32x4 acc[2][4];
  for (int nc = 0; nc < 10; ++nc) {
    const int sbase = nc * 64;
    int vn = SSZ - sbase; if (vn > 64) vn = 64;
    #pragma unroll
    for (int mt = 0; mt < 2; ++mt)
      #pragma unroll
      for (int nt = 0; nt < 4; ++nt) acc[mt][nt] = (f32x4){0.f,0.f,0.f,0.f};
    for (int kc = 0; kc < KCH; ++kc) {
      const int kbase = kc * 64;
      __syncthreads();
      #pragma unroll
      for (int i = 0; i < 8; ++i) {
        int lin = i * 256 + tid; int row = lin >> 4; int c4 = lin & 15;
        float4 v = make_float4(0.f,0.f,0.f,0.f);
        if (row < PN) v = *reinterpret_cast<const float4*>(Qb + (size_t)row * DIM + kbase + c4 * 4);
        ushort4 h; h.x=f2bf(v.x); h.y=f2bf(v.y); h.z=f2bf(v.z); h.w=f2bf(v.w);
        *reinterpret_cast<ushort4*>(&Qst[row][c4*4]) = h;
      }
      #pragma unroll
      for (int i = 0; i < 4; ++i) {
        int lin = i * 256 + tid; int row = lin >> 4; int c4 = lin & 15;
        int srow = sbase + row;
        float4 v = make_float4(0.f,0.f,0.f,0.f);
        if (srow < SSZ) v = *reinterpret_cast<const float4*>(Sb + (size_t)srow * DIM + kbase + c4 * 4);
        ushort4 h; h.x=f2bf(v.x); h.y=f2bf(v.y); h.z=f2bf(v.z); h.w=f2bf(v.w);
        *reinterpret_cast<ushort4*>(&Sst[row][c4*4]) = h;
      }
      __syncthreads();
      #pragma unroll
      for (int kk = 0; kk < 2; ++kk) {
        bf16x8 a0 = __builtin_bit_cast(bf16x8, *reinterpret_cast<const short8*>(&Qst[wv*32+ 0+l15][kk*32+quad*8]));
        bf16x8 a1 = __builtin_bit_cast(bf16x8, *reinterpret_cast<const short8*>(&Qst[wv*32+16+l15][kk*32+quad*8]));
        #pragma unroll
        for (int nt = 0; nt < 4; ++nt) {
          bf16x8 bb = __builtin_bit_cast(bf16x8, *reinterpret_cast<const short8*>(&Sst[nt*16+l15][kk*32+quad*8]));
          acc[0][nt] = __builtin_amdgcn_mfma_f32_16x16x32_bf16(a0, bb, acc[0][nt], 0,0,0);
          acc[1][nt] = __builtin_amdgcn_mfma_f32_16x16x32_bf16(a1, bb, acc[1][nt], 0,0,0);
        }
      }
    }
    #pragma unroll
    for (int mt = 0; mt < 2; ++mt)
      #pragma unroll
      for (int nt = 0; nt < 4; ++nt)
        #pragma unroll
        for (int r = 0; r < 4; ++r)
          Cs[wv*32+mt*16+quad*4+r][nt*16+l15] = acc[mt][nt][r];
    __syncthreads();
    {
      int row = tid >> 1; int half = tid & 1;
      float a = -3.0e38f, b2 = -3.0e38f, c = -3.0e38f;
      int c0 = half * 32; int cend = c0 + 32; if (cend > vn) cend = vn;
      for (int cc = c0; cc < cend; ++cc) ins3(a, b2, c, Cs[row][cc]);
      float o0 = __shfl_xor(a,1), o1 = __shfl_xor(b2,1), o2 = __shfl_xor(c,1);
      ins3(a,b2,c,o0); ins3(a,b2,c,o1); ins3(a,b2,c,o2);
      if (half == 0) {
        float r0=top3[row][0], r1=top3[row][1], r2=top3[row][2];
        ins3(r0,r1,r2,a); ins3(r0,r1,r2,b2); ins3(r0,r1,r2,c);
        top3[row][0]=r0; top3[row][1]=r1; top3[row][2]=r2;
      }
    }
    __syncthreads();
  }
  float s = 0.f;
  for (int i = tid; i < PN * TOPK; i += 256) s += top3[i/TOPK][i%TOPK];
  #pragma unroll
  for (int off = 32; off > 0; off >>= 1) s += __shfl_down(s, off);
  if (lane == 0) red[wv] = s;
  __syncthreads();
  if (tid == 0) out[bid] = (red[0]+red[1]+red[2]+red[3]) * (1.0f/(PN*TOPK));
}

// ---------------- launch ----------------
extern "C" void kernel_launch(void* const* d_in, const int* in_sizes, int n_in,
                              void* d_out, int out_size, void* d_ws, size_t ws_size,
                              hipStream_t stream) {
  const float* qf = (const float*)d_in[0];
  const float* sf = (const float*)d_in[1];
  float* out = (float*)d_out;
  (void)in_sizes; (void)n_in; (void)out_size;

  if (ws_size >= WS_NEED && d_ws != nullptr) {
    unsigned short* wq  = (unsigned short*)d_ws;
    unsigned short* wsp = wq + WSQ_BYTES / 2;
    cvt_pack<<<TOTCH / 256, 256, 0, stream>>>(qf, sf, wq, wsp);
    lpc_main<<<BATCH * NQ * WAY, 256, 0, stream>>>((const char*)wq, (const char*)wsp, out);
  } else {
    lpc_fallback<<<BATCH * NQ * WAY, 256, 0, stream>>>(qf, sf, out);
  }
}

// Round 4
// 647.052 us; speedup vs baseline: 5.9219x; 1.1724x over previous
//
#include <hip/hip_runtime.h>
#include <hip/hip_bf16.h>

// Problem constants:
#define BATCH 8
#define NQ    75
#define WAY   5
#define PN    121
#define DIM   640
#define SSZ   605        // shot * patch_num
#define TOPK  3

#define KCH 10           // DIM / 64
#define NCH 5            // 640 / 128

// Workspace: bf16, MFMA-tile-packed, XOR-swizzled (chunk_phys = chunk_log ^ (row&7)).
//   Q: [bq=600][kc=10][row=128][chunk=8]x16B  = 98,304,000 B
//   S: [bw=40][nc=5][kc=10][row=128][chunk=8] = 32,768,000 B
#define NQCH  (600 * 10 * 128 * 8)       // 6,144,000 Q chunks
#define NSCH  (40 * 5 * 10 * 128 * 8)    // 2,048,000 S chunks
#define TOTCH (NQCH + NSCH)              // 8,192,000
#define WSQ_BYTES ((size_t)NQCH * 16)
#define WS_NEED   ((size_t)TOTCH * 16)   // 131,072,000 B

typedef __attribute__((ext_vector_type(8))) short   short8;
typedef __attribute__((ext_vector_type(8))) __bf16  bf16x8;
typedef __attribute__((ext_vector_type(4))) float   f32x4;

__device__ inline unsigned short f2bf(float f) {
  unsigned u = __builtin_bit_cast(unsigned, f);
  return (unsigned short)((u + 0x7fffu + ((u >> 16) & 1u)) >> 16);
}

// branchless insert into sorted-descending triple: 1 max + 2 med3
__device__ inline void ins3(float &a, float &b, float &c, float v) {
  float na  = fmaxf(a, v);
  float nb  = __builtin_amdgcn_fmed3f(v, a, b);
  float nc2 = __builtin_amdgcn_fmed3f(v, b, c);
  a = na; b = nb; c = nc2;
}

// async 16B global->LDS (DMA; LDS dest = wave-uniform base + lane*16)
__device__ inline void async_copy16(const void* g, void* l) {
  __builtin_amdgcn_global_load_lds(
      (const __attribute__((address_space(1))) unsigned int*)g,
      (__attribute__((address_space(3))) unsigned int*)l, 16, 0, 0);
}

// ---------------- pack kernel: fp32 -> swizzled bf16 tiles in ws -------------
__global__ __launch_bounds__(256) void cvt_pack(const float* __restrict__ qf,
                                                const float* __restrict__ sf,
                                                unsigned short* __restrict__ wq,
                                                unsigned short* __restrict__ wsp) {
  int idx = blockIdx.x * 256 + threadIdx.x;
  union { ushort4 h[2]; uint4 v; } o;
  o.v = make_uint4(0u, 0u, 0u, 0u);
  if (idx < NQCH) {
    int p   = idx & 7;
    int row = (idx >> 3) & 127;
    int t   = idx >> 10;
    int kc  = t % KCH;
    int bq  = t / KCH;
    int c   = p ^ (row & 7);
    if (row < PN) {
      const float* g = qf + ((size_t)bq * PN + row) * DIM + kc * 64 + c * 8;
      float4 v0 = reinterpret_cast<const float4*>(g)[0];
      float4 v1 = reinterpret_cast<const float4*>(g)[1];
      o.h[0] = make_ushort4(f2bf(v0.x), f2bf(v0.y), f2bf(v0.z), f2bf(v0.w));
      o.h[1] = make_ushort4(f2bf(v1.x), f2bf(v1.y), f2bf(v1.z), f2bf(v1.w));
    }
    reinterpret_cast<uint4*>(wq)[idx] = o.v;
  } else if (idx < TOTCH) {
    int si  = idx - NQCH;
    int p   = si & 7;
    int row = (si >> 3) & 127;
    int t   = si >> 10;
    int kc  = t % KCH;
    int u   = t / KCH;
    int nc  = u % NCH;
    int bw  = u / NCH;
    int srow = nc * 128 + row;
    int c   = p ^ (row & 7);
    if (srow < SSZ) {
      const float* g = sf + ((size_t)bw * SSZ + srow) * DIM + kc * 64 + c * 8;
      float4 v0 = reinterpret_cast<const float4*>(g)[0];
      float4 v1 = reinterpret_cast<const float4*>(g)[1];
      o.h[0] = make_ushort4(f2bf(v0.x), f2bf(v0.y), f2bf(v0.z), f2bf(v0.w));
      o.h[1] = make_ushort4(f2bf(v1.x), f2bf(v1.y), f2bf(v1.z), f2bf(v1.w));
    }
    reinterpret_cast<uint4*>(wsp)[si] = o.v;
  }
}

// ---------------- main kernel ----------------
// One block per (b,q,w), XCD-swizzled so XCD k owns b=k: per-XCD working set =
// 5 S slabs (4 MB, exactly one L2) + one Q slab at a time (5 consecutive
// w-blocks share it). 4 waves = 64x64 quadrants; DMA staging; XOR-swizzled
// LDS reads (0 conflicts, r3); per-row top-3 in registers.
__global__ __launch_bounds__(256, 4) void lpc_main(
    const char* __restrict__ wq,    // packed Q tiles
    const char* __restrict__ wsp,   // packed S tiles
    float* __restrict__ out)        // [B, NQ, WAY]
{
  __shared__ char Qs[16384];
  __shared__ char Ss[16384];
  __shared__ float red[4];

  // XCD swizzle: consecutive blockIdx round-robin over 8 XCDs; remap so XCD k
  // processes contiguous bid range [k*375, (k+1)*375) == batch element k.
  const int sbid = blockIdx.x;
  const int bid  = (sbid & 7) * (NQ * WAY) + (sbid >> 3);

  const int w   = bid % WAY;
  const int bq  = bid / WAY;            // b*NQ + q
  const int b   = bid / (WAY * NQ);

  const char* Qtiles = wq  + (size_t)bq * KCH * 16384;
  const char* Stiles = wsp + (size_t)(b * WAY + w) * NCH * KCH * 16384;

  const int tid  = threadIdx.x;
  const int lane = tid & 63;
  const int wv   = tid >> 6;
  const int l15  = lane & 15;
  const int quad = lane >> 4;
  const int mrow0 = (wv >> 1) * 64;     // quadrant row base
  const int ncol0 = (wv & 1) * 64;      // quadrant col base

  // swizzled chunk byte offsets (XOR distributes over the <<4)
  const int sw16 = (l15 & 7) * 16;
  const int cp0  = (quad * 16) ^ sw16;        // kk = 0
  const int cp1  = ((4 + quad) * 16) ^ sw16;  // kk = 1

  const char* qb = Qs + (mrow0 + l15) * 128;
  const char* sb = Ss + (ncol0 + l15) * 128;

  // per-lane running top-3 for 16 owned rows: row = mrow0 + mt*16 + quad*4 + r
  float t3a[4][4], t3b[4][4], t3c[4][4];
  #pragma unroll
  for (int mt = 0; mt < 4; ++mt)
    #pragma unroll
    for (int r = 0; r < 4; ++r) {
      t3a[mt][r] = -3.0e38f; t3b[mt][r] = -3.0e38f; t3c[mt][r] = -3.0e38f;
    }

  for (int nc = 0; nc < NCH; ++nc) {
    f32x4 acc[4][4];
    #pragma unroll
    for (int mt = 0; mt < 4; ++mt)
      #pragma unroll
      for (int nt = 0; nt < 4; ++nt)
        acc[mt][nt] = (f32x4){0.f, 0.f, 0.f, 0.f};

    #pragma unroll 1
    for (int kc = 0; kc < KCH; ++kc) {
      __syncthreads();   // previous iteration's readers done
      {
        const char* qsl = Qtiles + (size_t)kc * 16384;
        const char* ssl = Stiles + ((size_t)nc * KCH + kc) * 16384;
        #pragma unroll
        for (int i = 0; i < 4; ++i) {
          int ch = wv * 4 + i;
          async_copy16(qsl + ch * 1024 + lane * 16, Qs + ch * 1024);
          async_copy16(ssl + ch * 1024 + lane * 16, Ss + ch * 1024);
        }
      }
      __syncthreads();   // drains vmcnt (DMA complete)

      #pragma unroll
      for (int kk = 0; kk < 2; ++kk) {
        const int cp = kk ? cp1 : cp0;
        short8 a[4], bf[4];
        #pragma unroll
        for (int mt = 0; mt < 4; ++mt)
          a[mt] = *reinterpret_cast<const short8*>(qb + mt * 2048 + cp);
        #pragma unroll
        for (int nt = 0; nt < 4; ++nt)
          bf[nt] = *reinterpret_cast<const short8*>(sb + nt * 2048 + cp);
        #pragma unroll
        for (int mt = 0; mt < 4; ++mt)
          #pragma unroll
          for (int nt = 0; nt < 4; ++nt)
            acc[mt][nt] = __builtin_amdgcn_mfma_f32_16x16x32_bf16(
                __builtin_bit_cast(bf16x8, a[mt]),
                __builtin_bit_cast(bf16x8, bf[nt]), acc[mt][nt], 0, 0, 0);
      }
    }

    // fold this 128-col chunk into register top-3 (mask pad cols >= 605)
    #pragma unroll
    for (int nt = 0; nt < 4; ++nt) {
      int col = nc * 128 + ncol0 + nt * 16 + l15;
      bool valid = col < SSZ;
      #pragma unroll
      for (int mt = 0; mt < 4; ++mt)
        #pragma unroll
        for (int r = 0; r < 4; ++r) {
          float v = valid ? acc[mt][nt][r] : -3.0e38f;
          ins3(t3a[mt][r], t3b[mt][r], t3c[mt][r], v);
        }
    }
  }

  // butterfly-merge top-3 across the 16 l15 lanes (same rows, different cols)
  #pragma unroll
  for (int m = 1; m < 16; m <<= 1) {
    #pragma unroll
    for (int mt = 0; mt < 4; ++mt)
      #pragma unroll
      for (int r = 0; r < 4; ++r) {
        float o0 = __shfl_xor(t3a[mt][r], m);
        float o1 = __shfl_xor(t3b[mt][r], m);
        float o2 = __shfl_xor(t3c[mt][r], m);
        ins3(t3a[mt][r], t3b[mt][r], t3c[mt][r], o0);
        ins3(t3a[mt][r], t3b[mt][r], t3c[mt][r], o1);
        ins3(t3a[mt][r], t3b[mt][r], t3c[mt][r], o2);
      }
  }

  // cross-half merge via LDS scratch (reuse Qs): waves 1,3 publish; 0,2 merge
  float* tb = reinterpret_cast<float*>(Qs);   // [128][3]
  __syncthreads();
  if ((wv & 1) == 1 && l15 == 0) {
    #pragma unroll
    for (int mt = 0; mt < 4; ++mt)
      #pragma unroll
      for (int r = 0; r < 4; ++r) {
        int row = mrow0 + mt * 16 + quad * 4 + r;
        tb[row * 3 + 0] = t3a[mt][r];
        tb[row * 3 + 1] = t3b[mt][r];
        tb[row * 3 + 2] = t3c[mt][r];
      }
  }
  __syncthreads();
  if ((wv & 1) == 0 && l15 == 0) {
    #pragma unroll
    for (int mt = 0; mt < 4; ++mt)
      #pragma unroll
      for (int r = 0; r < 4; ++r) {
        int row = mrow0 + mt * 16 + quad * 4 + r;
        ins3(t3a[mt][r], t3b[mt][r], t3c[mt][r], tb[row * 3 + 0]);
        ins3(t3a[mt][r], t3b[mt][r], t3c[mt][r], tb[row * 3 + 1]);
        ins3(t3a[mt][r], t3b[mt][r], t3c[mt][r], tb[row * 3 + 2]);
      }
  }
  __syncthreads();
  if ((wv & 1) == 0 && l15 == 0) {
    #pragma unroll
    for (int mt = 0; mt < 4; ++mt)
      #pragma unroll
      for (int r = 0; r < 4; ++r) {
        int row = mrow0 + mt * 16 + quad * 4 + r;
        tb[row * 3 + 0] = t3a[mt][r];
        tb[row * 3 + 1] = t3b[mt][r];
        tb[row * 3 + 2] = t3c[mt][r];
      }
  }
  __syncthreads();

  // mean over valid rows (<121) and k
  float s = 0.f;
  for (int i = tid; i < PN * TOPK; i += 256) s += tb[i];
  #pragma unroll
  for (int off = 32; off > 0; off >>= 1) s += __shfl_down(s, off);
  if (lane == 0) red[wv] = s;
  __syncthreads();
  if (tid == 0)
    out[bid] = (red[0] + red[1] + red[2] + red[3]) * (1.0f / (PN * TOPK));
}

// ---------------- fallback (direct from fp32, only if ws too small) ---------
__global__ __launch_bounds__(256) void lpc_fallback(
    const float* __restrict__ qf, const float* __restrict__ sf,
    float* __restrict__ out)
{
  __shared__ short Qst[128][72];
  __shared__ short Sst[64][72];
  __shared__ float Cs[128][67];
  __shared__ float top3[128][TOPK];
  __shared__ float red[4];

  const int bid = blockIdx.x;
  const int w   = bid % WAY;
  const int qi  = (bid / WAY) % NQ;
  const int b   = bid / (WAY * NQ);
  const float* Qb = qf + ((size_t)(b * NQ + qi)) * PN * DIM;
  const float* Sb = sf + ((size_t)(b * WAY + w)) * SSZ * DIM;
  const int tid  = threadIdx.x;
  const int lane = tid & 63;
  const int wv   = tid >> 6;
  const int l15  = lane & 15;
  const int quad = lane >> 4;

  if (tid < 128) { top3[tid][0] = -3.0e38f; top3[tid][1] = -3.0e38f; top3[tid][2] = -3.0e38f; }
  f32x4 acc[2][4];
  for (int nc = 0; nc < 10; ++nc) {
    const int sbase = nc * 64;
    int vn = SSZ - sbase; if (vn > 64) vn = 64;
    #pragma unroll
    for (int mt = 0; mt < 2; ++mt)
      #pragma unroll
      for (int nt = 0; nt < 4; ++nt) acc[mt][nt] = (f32x4){0.f,0.f,0.f,0.f};
    for (int kc = 0; kc < KCH; ++kc) {
      const int kbase = kc * 64;
      __syncthreads();
      #pragma unroll
      for (int i = 0; i < 8; ++i) {
        int lin = i * 256 + tid; int row = lin >> 4; int c4 = lin & 15;
        float4 v = make_float4(0.f,0.f,0.f,0.f);
        if (row < PN) v = *reinterpret_cast<const float4*>(Qb + (size_t)row * DIM + kbase + c4 * 4);
        ushort4 h; h.x=f2bf(v.x); h.y=f2bf(v.y); h.z=f2bf(v.z); h.w=f2bf(v.w);
        *reinterpret_cast<ushort4*>(&Qst[row][c4*4]) = h;
      }
      #pragma unroll
      for (int i = 0; i < 4; ++i) {
        int lin = i * 256 + tid; int row = lin >> 4; int c4 = lin & 15;
        int srow = sbase + row;
        float4 v = make_float4(0.f,0.f,0.f,0.f);
        if (srow < SSZ) v = *reinterpret_cast<const float4*>(Sb + (size_t)srow * DIM + kbase + c4 * 4);
        ushort4 h; h.x=f2bf(v.x); h.y=f2bf(v.y); h.z=f2bf(v.z); h.w=f2bf(v.w);
        *reinterpret_cast<ushort4*>(&Sst[row][c4*4]) = h;
      }
      __syncthreads();
      #pragma unroll
      for (int kk = 0; kk < 2; ++kk) {
        bf16x8 a0 = __builtin_bit_cast(bf16x8, *reinterpret_cast<const short8*>(&Qst[wv*32+ 0+l15][kk*32+quad*8]));
        bf16x8 a1 = __builtin_bit_cast(bf16x8, *reinterpret_cast<const short8*>(&Qst[wv*32+16+l15][kk*32+quad*8]));
        #pragma unroll
        for (int nt = 0; nt < 4; ++nt) {
          bf16x8 bb = __builtin_bit_cast(bf16x8, *reinterpret_cast<const short8*>(&Sst[nt*16+l15][kk*32+quad*8]));
          acc[0][nt] = __builtin_amdgcn_mfma_f32_16x16x32_bf16(a0, bb, acc[0][nt], 0,0,0);
          acc[1][nt] = __builtin_amdgcn_mfma_f32_16x16x32_bf16(a1, bb, acc[1][nt], 0,0,0);
        }
      }
    }
    #pragma unroll
    for (int mt = 0; mt < 2; ++mt)
      #pragma unroll
      for (int nt = 0; nt < 4; ++nt)
        #pragma unroll
        for (int r = 0; r < 4; ++r)
          Cs[wv*32+mt*16+quad*4+r][nt*16+l15] = acc[mt][nt][r];
    __syncthreads();
    {
      int row = tid >> 1; int half = tid & 1;
      float a = -3.0e38f, b2 = -3.0e38f, c = -3.0e38f;
      int c0 = half * 32; int cend = c0 + 32; if (cend > vn) cend = vn;
      for (int cc = c0; cc < cend; ++cc) ins3(a, b2, c, Cs[row][cc]);
      float o0 = __shfl_xor(a,1), o1 = __shfl_xor(b2,1), o2 = __shfl_xor(c,1);
      ins3(a,b2,c,o0); ins3(a,b2,c,o1); ins3(a,b2,c,o2);
      if (half == 0) {
        float r0=top3[row][0], r1=top3[row][1], r2=top3[row][2];
        ins3(r0,r1,r2,a); ins3(r0,r1,r2,b2); ins3(r0,r1,r2,c);
        top3[row][0]=r0; top3[row][1]=r1; top3[row][2]=r2;
      }
    }
    __syncthreads();
  }
  float s = 0.f;
  for (int i = tid; i < PN * TOPK; i += 256) s += top3[i/TOPK][i%TOPK];
  #pragma unroll
  for (int off = 32; off > 0; off >>= 1) s += __shfl_down(s, off);
  if (lane == 0) red[wv] = s;
  __syncthreads();
  if (tid == 0) out[bid] = (red[0]+red[1]+red[2]+red[3]) * (1.0f/(PN*TOPK));
}

// ---------------- launch ----------------
extern "C" void kernel_launch(void* const* d_in, const int* in_sizes, int n_in,
                              void* d_out, int out_size, void* d_ws, size_t ws_size,
                              hipStream_t stream) {
  const float* qf = (const float*)d_in[0];
  const float* sf = (const float*)d_in[1];
  float* out = (float*)d_out;
  (void)in_sizes; (void)n_in; (void)out_size;

  if (ws_size >= WS_NEED && d_ws != nullptr) {
    unsigned short* wq  = (unsigned short*)d_ws;
    unsigned short* wsp = wq + WSQ_BYTES / 2;
    cvt_pack<<<TOTCH / 256, 256, 0, stream>>>(qf, sf, wq, wsp);
    lpc_main<<<BATCH * NQ * WAY, 256, 0, stream>>>((const char*)wq, (const char*)wsp, out);
  } else {
    lpc_fallback<<<BATCH * NQ * WAY, 256, 0, stream>>>(qf, sf, out);
  }
}

// Round 5
// 621.553 us; speedup vs baseline: 6.1649x; 1.0410x over previous
//
#include <hip/hip_runtime.h>
#include <hip/hip_bf16.h>

// Problem constants:
#define BATCH 8
#define NQ    75
#define WAY   5
#define PN    121
#define DIM   640
#define SSZ   605        // shot * patch_num
#define TOPK  3

#define KCH 10           // DIM / 64
#define NCH 5            // 640 / 128

// Workspace: bf16, MFMA-tile-packed, XOR-swizzled (chunk_phys = chunk_log ^ (row&7)).
//   Q: [bq=600][kc=10] tiles of [row=128][chunk=8]x16B  (6000 tiles)
//   S: [bw=40][nc=5][kc=10] tiles                        (2000 tiles)
#define NQTILES 6000
#define NSTILES 2000
#define WSQ_BYTES ((size_t)NQTILES * 16384)
#define WS_NEED   ((size_t)(NQTILES + NSTILES) * 16384)   // 131,072,000 B

typedef __attribute__((ext_vector_type(8))) short   short8;
typedef __attribute__((ext_vector_type(8))) __bf16  bf16x8;
typedef __attribute__((ext_vector_type(4))) float   f32x4;

__device__ inline unsigned short f2bf(float f) {
  unsigned u = __builtin_bit_cast(unsigned, f);
  return (unsigned short)((u + 0x7fffu + ((u >> 16) & 1u)) >> 16);
}
__device__ inline unsigned pk2(float lo, float hi) {
  return (unsigned)f2bf(lo) | ((unsigned)f2bf(hi) << 16);
}

// branchless insert into sorted-descending triple: 1 max + 2 med3
__device__ inline void ins3(float &a, float &b, float &c, float v) {
  float na  = fmaxf(a, v);
  float nb  = __builtin_amdgcn_fmed3f(v, a, b);
  float nc2 = __builtin_amdgcn_fmed3f(v, b, c);
  a = na; b = nb; c = nc2;
}

// async 16B global->LDS (DMA; LDS dest = wave-uniform base + lane*16)
__device__ inline void async_copy16(const void* g, void* l) {
  __builtin_amdgcn_global_load_lds(
      (const __attribute__((address_space(1))) unsigned int*)g,
      (__attribute__((address_space(3))) unsigned int*)l, 16, 0, 0);
}

// ---------------- pack kernel: fp32 -> swizzled bf16 tiles in ws -------------
// One block per 16 KB output tile. 256 threads x 4 chunks (64 B out, 128 B in
// each). All per-thread index math is shifts/masks; the tile decomposition is
// one uniform scalar divide per block.
__global__ __launch_bounds__(256) void cvt_pack(const float* __restrict__ qf,
                                                const float* __restrict__ sf,
                                                uint4* __restrict__ wq,
                                                uint4* __restrict__ wsp) {
  const int blk = blockIdx.x;
  const float* src;
  uint4* dst;
  int nrows;
  if (blk < NQTILES) {
    int kc = blk % KCH;
    int bq = blk / KCH;
    src = qf + (size_t)bq * PN * DIM + kc * 64;
    dst = wq + (size_t)blk * 1024;
    nrows = PN;
  } else {
    int t  = blk - NQTILES;          // ((bw*5 + nc)*10 + kc)
    int kc = t % KCH;
    int u  = t / KCH;
    int nc = u % NCH;
    int bw = u / NCH;
    src = sf + ((size_t)bw * SSZ + nc * 128) * DIM + kc * 64;
    dst = wsp + (size_t)t * 1024;
    nrows = SSZ - nc * 128; if (nrows > 128) nrows = 128;
  }
  #pragma unroll
  for (int i = 0; i < 4; ++i) {
    int ch  = i * 256 + threadIdx.x;   // 0..1023
    int p   = ch & 7;
    int row = ch >> 3;
    int c   = p ^ (row & 7);           // logical chunk for this physical slot
    uint4 o = make_uint4(0u, 0u, 0u, 0u);
    if (row < nrows) {
      const float* g = src + (size_t)row * DIM + c * 8;
      float4 v0 = reinterpret_cast<const float4*>(g)[0];
      float4 v1 = reinterpret_cast<const float4*>(g)[1];
      o.x = pk2(v0.x, v0.y); o.y = pk2(v0.z, v0.w);
      o.z = pk2(v1.x, v1.y); o.w = pk2(v1.z, v1.w);
    }
    dst[ch] = o;
  }
}

// ---------------- main kernel ----------------
// One block per (b,q,w), XCD-swizzled so XCD k owns b=k (per-XCD working set:
// 5 S slabs = 4 MB = one L2, plus one 160 KB Q slab shared by 5 w-blocks).
// 4 waves = 64x64 quadrants; DMA staging; XOR-swizzled LDS reads (0 conflicts,
// r3); per-row top-3 in registers.
// __launch_bounds__(256,3): reg cap 170 = 64 AGPR acc + ~106 VGPR — fits the
// live set (t3=48, frags=32, addr) with NO spills; (256,4) capped at 128 and
// spilled 246 MB (r4).
__global__ __launch_bounds__(256, 3) void lpc_main(
    const char* __restrict__ wq,    // packed Q tiles
    const char* __restrict__ wsp,   // packed S tiles
    float* __restrict__ out)        // [B, NQ, WAY]
{
  __shared__ char Qs[16384];
  __shared__ char Ss[16384];
  __shared__ float red[4];

  // XCD swizzle: consecutive blockIdx round-robin over 8 XCDs; remap so XCD k
  // processes contiguous bid range [k*375, (k+1)*375) == batch element k.
  const int sbid = blockIdx.x;
  const int bid  = (sbid & 7) * (NQ * WAY) + (sbid >> 3);

  const int w   = bid % WAY;
  const int bq  = bid / WAY;            // b*NQ + q
  const int b   = bid / (WAY * NQ);

  const char* Qtiles = wq  + (size_t)bq * KCH * 16384;
  const char* Stiles = wsp + (size_t)(b * WAY + w) * NCH * KCH * 16384;

  const int tid  = threadIdx.x;
  const int lane = tid & 63;
  const int wv   = tid >> 6;
  const int l15  = lane & 15;
  const int quad = lane >> 4;
  const int mrow0 = (wv >> 1) * 64;     // quadrant row base
  const int ncol0 = (wv & 1) * 64;      // quadrant col base

  // swizzled chunk byte offsets (XOR distributes over the <<4)
  const int sw16 = (l15 & 7) * 16;
  const int cp0  = (quad * 16) ^ sw16;        // kk = 0
  const int cp1  = ((4 + quad) * 16) ^ sw16;  // kk = 1

  const char* qb = Qs + (mrow0 + l15) * 128;
  const char* sb = Ss + (ncol0 + l15) * 128;

  // per-lane running top-3 for 16 owned rows: row = mrow0 + mt*16 + quad*4 + r
  float t3a[4][4], t3b[4][4], t3c[4][4];
  #pragma unroll
  for (int mt = 0; mt < 4; ++mt)
    #pragma unroll
    for (int r = 0; r < 4; ++r) {
      t3a[mt][r] = -3.0e38f; t3b[mt][r] = -3.0e38f; t3c[mt][r] = -3.0e38f;
    }

  for (int nc = 0; nc < NCH; ++nc) {
    f32x4 acc[4][4];
    #pragma unroll
    for (int mt = 0; mt < 4; ++mt)
      #pragma unroll
      for (int nt = 0; nt < 4; ++nt)
        acc[mt][nt] = (f32x4){0.f, 0.f, 0.f, 0.f};

    #pragma unroll 1
    for (int kc = 0; kc < KCH; ++kc) {
      __syncthreads();   // previous iteration's readers done
      {
        const char* qsl = Qtiles + (size_t)kc * 16384;
        const char* ssl = Stiles + ((size_t)nc * KCH + kc) * 16384;
        #pragma unroll
        for (int i = 0; i < 4; ++i) {
          int ch = wv * 4 + i;
          async_copy16(qsl + ch * 1024 + lane * 16, Qs + ch * 1024);
          async_copy16(ssl + ch * 1024 + lane * 16, Ss + ch * 1024);
        }
      }
      __syncthreads();   // drains vmcnt (DMA complete)

      #pragma unroll
      for (int kk = 0; kk < 2; ++kk) {
        const int cp = kk ? cp1 : cp0;
        short8 a[4], bf[4];
        #pragma unroll
        for (int mt = 0; mt < 4; ++mt)
          a[mt] = *reinterpret_cast<const short8*>(qb + mt * 2048 + cp);
        #pragma unroll
        for (int nt = 0; nt < 4; ++nt)
          bf[nt] = *reinterpret_cast<const short8*>(sb + nt * 2048 + cp);
        #pragma unroll
        for (int mt = 0; mt < 4; ++mt)
          #pragma unroll
          for (int nt = 0; nt < 4; ++nt)
            acc[mt][nt] = __builtin_amdgcn_mfma_f32_16x16x32_bf16(
                __builtin_bit_cast(bf16x8, a[mt]),
                __builtin_bit_cast(bf16x8, bf[nt]), acc[mt][nt], 0, 0, 0);
      }
    }

    // fold this 128-col chunk into register top-3 (mask pad cols >= 605)
    #pragma unroll
    for (int nt = 0; nt < 4; ++nt) {
      int col = nc * 128 + ncol0 + nt * 16 + l15;
      bool valid = col < SSZ;
      #pragma unroll
      for (int mt = 0; mt < 4; ++mt)
        #pragma unroll
        for (int r = 0; r < 4; ++r) {
          float v = valid ? acc[mt][nt][r] : -3.0e38f;
          ins3(t3a[mt][r], t3b[mt][r], t3c[mt][r], v);
        }
    }
  }

  // butterfly-merge top-3 across the 16 l15 lanes (same rows, different cols)
  #pragma unroll
  for (int m = 1; m < 16; m <<= 1) {
    #pragma unroll
    for (int mt = 0; mt < 4; ++mt)
      #pragma unroll
      for (int r = 0; r < 4; ++r) {
        float o0 = __shfl_xor(t3a[mt][r], m);
        float o1 = __shfl_xor(t3b[mt][r], m);
        float o2 = __shfl_xor(t3c[mt][r], m);
        ins3(t3a[mt][r], t3b[mt][r], t3c[mt][r], o0);
        ins3(t3a[mt][r], t3b[mt][r], t3c[mt][r], o1);
        ins3(t3a[mt][r], t3b[mt][r], t3c[mt][r], o2);
      }
  }

  // cross-half merge via LDS scratch (reuse Qs): waves 1,3 publish; 0,2 merge
  float* tb = reinterpret_cast<float*>(Qs);   // [128][3]
  __syncthreads();
  if ((wv & 1) == 1 && l15 == 0) {
    #pragma unroll
    for (int mt = 0; mt < 4; ++mt)
      #pragma unroll
      for (int r = 0; r < 4; ++r) {
        int row = mrow0 + mt * 16 + quad * 4 + r;
        tb[row * 3 + 0] = t3a[mt][r];
        tb[row * 3 + 1] = t3b[mt][r];
        tb[row * 3 + 2] = t3c[mt][r];
      }
  }
  __syncthreads();
  if ((wv & 1) == 0 && l15 == 0) {
    #pragma unroll
    for (int mt = 0; mt < 4; ++mt)
      #pragma unroll
      for (int r = 0; r < 4; ++r) {
        int row = mrow0 + mt * 16 + quad * 4 + r;
        ins3(t3a[mt][r], t3b[mt][r], t3c[mt][r], tb[row * 3 + 0]);
        ins3(t3a[mt][r], t3b[mt][r], t3c[mt][r], tb[row * 3 + 1]);
        ins3(t3a[mt][r], t3b[mt][r], t3c[mt][r], tb[row * 3 + 2]);
      }
  }
  __syncthreads();
  if ((wv & 1) == 0 && l15 == 0) {
    #pragma unroll
    for (int mt = 0; mt < 4; ++mt)
      #pragma unroll
      for (int r = 0; r < 4; ++r) {
        int row = mrow0 + mt * 16 + quad * 4 + r;
        tb[row * 3 + 0] = t3a[mt][r];
        tb[row * 3 + 1] = t3b[mt][r];
        tb[row * 3 + 2] = t3c[mt][r];
      }
  }
  __syncthreads();

  // mean over valid rows (<121) and k
  float s = 0.f;
  for (int i = tid; i < PN * TOPK; i += 256) s += tb[i];
  #pragma unroll
  for (int off = 32; off > 0; off >>= 1) s += __shfl_down(s, off);
  if (lane == 0) red[wv] = s;
  __syncthreads();
  if (tid == 0)
    out[bid] = (red[0] + red[1] + red[2] + red[3]) * (1.0f / (PN * TOPK));
}

// ---------------- fallback (direct from fp32, only if ws too small) ---------
__global__ __launch_bounds__(256) void lpc_fallback(
    const float* __restrict__ qf, const float* __restrict__ sf,
    float* __restrict__ out)
{
  __shared__ short Qst[128][72];
  __shared__ short Sst[64][72];
  __shared__ float Cs[128][67];
  __shared__ float top3[128][TOPK];
  __shared__ float red[4];

  const int bid = blockIdx.x;
  const int w   = bid % WAY;
  const int qi  = (bid / WAY) % NQ;
  const int b   = bid / (WAY * NQ);
  const float* Qb = qf + ((size_t)(b * NQ + qi)) * PN * DIM;
  const float* Sb = sf + ((size_t)(b * WAY + w)) * SSZ * DIM;
  const int tid  = threadIdx.x;
  const int lane = tid & 63;
  const int wv   = tid >> 6;
  const int l15  = lane & 15;
  const int quad = lane >> 4;

  if (tid < 128) { top3[tid][0] = -3.0e38f; top3[tid][1] = -3.0e38f; top3[tid][2] = -3.0e38f; }
  f32x4 acc[2][4];
  for (int nc = 0; nc < 10; ++nc) {
    const int sbase = nc * 64;
    int vn = SSZ - sbase; if (vn > 64) vn = 64;
    #pragma unroll
    for (int mt = 0; mt < 2; ++mt)
      #pragma unroll
      for (int nt = 0; nt < 4; ++nt) acc[mt][nt] = (f32x4){0.f,0.f,0.f,0.f};
    for (int kc = 0; kc < KCH; ++kc) {
      const int kbase = kc * 64;
      __syncthreads();
      #pragma unroll
      for (int i = 0; i < 8; ++i) {
        int lin = i * 256 + tid; int row = lin >> 4; int c4 = lin & 15;
        float4 v = make_float4(0.f,0.f,0.f,0.f);
        if (row < PN) v = *reinterpret_cast<const float4*>(Qb + (size_t)row * DIM + kbase + c4 * 4);
        ushort4 h; h.x=f2bf(v.x); h.y=f2bf(v.y); h.z=f2bf(v.z); h.w=f2bf(v.w);
        *reinterpret_cast<ushort4*>(&Qst[row][c4*4]) = h;
      }
      #pragma unroll
      for (int i = 0; i < 4; ++i) {
        int lin = i * 256 + tid; int row = lin >> 4; int c4 = lin & 15;
        int srow = sbase + row;
        float4 v = make_float4(0.f,0.f,0.f,0.f);
        if (srow < SSZ) v = *reinterpret_cast<const float4*>(Sb + (size_t)srow * DIM + kbase + c4 * 4);
        ushort4 h; h.x=f2bf(v.x); h.y=f2bf(v.y); h.z=f2bf(v.z); h.w=f2bf(v.w);
        *reinterpret_cast<ushort4*>(&Sst[row][c4*4]) = h;
      }
      __syncthreads();
      #pragma unroll
      for (int kk = 0; kk < 2; ++kk) {
        bf16x8 a0 = __builtin_bit_cast(bf16x8, *reinterpret_cast<const short8*>(&Qst[wv*32+ 0+l15][kk*32+quad*8]));
        bf16x8 a1 = __builtin_bit_cast(bf16x8, *reinterpret_cast<const short8*>(&Qst[wv*32+16+l15][kk*32+quad*8]));
        #pragma unroll
        for (int nt = 0; nt < 4; ++nt) {
          bf16x8 bb = __builtin_bit_cast(bf16x8, *reinterpret_cast<const short8*>(&Sst[nt*16+l15][kk*32+quad*8]));
          acc[0][nt] = __builtin_amdgcn_mfma_f32_16x16x32_bf16(a0, bb, acc[0][nt], 0,0,0);
          acc[1][nt] = __builtin_amdgcn_mfma_f32_16x16x32_bf16(a1, bb, acc[1][nt], 0,0,0);
        }
      }
    }
    #pragma unroll
    for (int mt = 0; mt < 2; ++mt)
      #pragma unroll
      for (int nt = 0; nt < 4; ++nt)
        #pragma unroll
        for (int r = 0; r < 4; ++r)
          Cs[wv*32+mt*16+quad*4+r][nt*16+l15] = acc[mt][nt][r];
    __syncthreads();
    {
      int row = tid >> 1; int half = tid & 1;
      float a = -3.0e38f, b2 = -3.0e38f, c = -3.0e38f;
      int c0 = half * 32; int cend = c0 + 32; if (cend > vn) cend = vn;
      for (int cc = c0; cc < cend; ++cc) ins3(a, b2, c, Cs[row][cc]);
      float o0 = __shfl_xor(a,1), o1 = __shfl_xor(b2,1), o2 = __shfl_xor(c,1);
      ins3(a,b2,c,o0); ins3(a,b2,c,o1); ins3(a,b2,c,o2);
      if (half == 0) {
        float r0=top3[row][0], r1=top3[row][1], r2=top3[row][2];
        ins3(r0,r1,r2,a); ins3(r0,r1,r2,b2); ins3(r0,r1,r2,c);
        top3[row][0]=r0; top3[row][1]=r1; top3[row][2]=r2;
      }
    }
    __syncthreads();
  }
  float s = 0.f;
  for (int i = tid; i < PN * TOPK; i += 256) s += top3[i/TOPK][i%TOPK];
  #pragma unroll
  for (int off = 32; off > 0; off >>= 1) s += __shfl_down(s, off);
  if (lane == 0) red[wv] = s;
  __syncthreads();
  if (tid == 0) out[bid] = (red[0]+red[1]+red[2]+red[3]) * (1.0f/(PN*TOPK));
}

// ---------------- launch ----------------
extern "C" void kernel_launch(void* const* d_in, const int* in_sizes, int n_in,
                              void* d_out, int out_size, void* d_ws, size_t ws_size,
                              hipStream_t stream) {
  const float* qf = (const float*)d_in[0];
  const float* sf = (const float*)d_in[1];
  float* out = (float*)d_out;
  (void)in_sizes; (void)n_in; (void)out_size;

  if (ws_size >= WS_NEED && d_ws != nullptr) {
    uint4* wq  = (uint4*)d_ws;
    uint4* wsp = wq + (size_t)NQTILES * 1024;
    cvt_pack<<<NQTILES + NSTILES, 256, 0, stream>>>(qf, sf, wq, wsp);
    lpc_main<<<BATCH * NQ * WAY, 256, 0, stream>>>((const char*)wq, (const char*)wsp, out);
  } else {
    lpc_fallback<<<BATCH * NQ * WAY, 256, 0, stream>>>(qf, sf, out);
  }
}